// Round 1
// 240.634 us; speedup vs baseline: 1.0546x; 1.0546x over previous
//
#include <hip/hip_runtime.h>
#include <hip/hip_fp16.h>

// GATConv: N=50000, E=1600000, DIM_IN=256, HEADS=4, DIM_OUT=32 (HC=128)
// R11: agg_kernel restructured to 4 edge-groups x 16 lanes (8 ch/lane, 16B gathers),
//      shfl_xor cross-group reduce; csr_kernel widened to 1024 threads;
//      zero_kernel folded into wtrans_kernel.
// proj = f16 MFMA GEMM (R9); escore edge-parallel (R10).

#define DIN 256
#define HC 128
#define NH 4
#define NEG 0.2f
#define BSH 8
#define BSZ 256

typedef _Float16 half8 __attribute__((ext_vector_type(8)));
typedef _Float16 half2v __attribute__((ext_vector_type(2)));
typedef float f32x4 __attribute__((ext_vector_type(4)));

// ---------------- W transpose + f16 convert + zero ghist ----------------
__global__ __launch_bounds__(256) void wtrans_kernel(const float* __restrict__ W,
                                                     _Float16* __restrict__ Wt,
                                                     int* __restrict__ ghist) {
    int i = blockIdx.x * 256 + threadIdx.x;
    if (i < 257) ghist[i] = 0;
    int k = i >> 7, c = i & 127;
    Wt[c * 256 + k] = (_Float16)W[i];
}

// ---------------- projection via MFMA + fused attention logits ----------------
__global__ __launch_bounds__(256) void proj_kernel(const float* __restrict__ x,
                                                   const _Float16* __restrict__ Wt,
                                                   const float* __restrict__ attS,
                                                   const float* __restrict__ attD,
                                                   __half* __restrict__ xph,
                                                   float* __restrict__ a_src,
                                                   float* __restrict__ a_dst, int n) {
    __shared__ _Float16 smem[8704];
    __shared__ float attSL[128], attDL[128];
    _Float16* xs = smem;                      // [64][40]
    _Float16* Wl = smem + 2560;               // [128][40]
    _Float16* ep = smem;                      // [64][136]

    const int tid  = threadIdx.x;
    const int node0 = blockIdx.x * 64;
    const int wave = tid >> 6;
    const int lane = tid & 63;
    const int l15  = lane & 15;
    const int quad = lane >> 4;

    if (tid < 128) attSL[tid] = attS[tid];
    else           attDL[tid - 128] = attD[tid - 128];

    f32x4 acc[8];
#pragma unroll
    for (int ct = 0; ct < 8; ++ct) acc[ct] = (f32x4){0.f, 0.f, 0.f, 0.f};

    for (int kt = 0; kt < DIN; kt += 32) {
        __syncthreads();
#pragma unroll
        for (int r = 0; r < 4; ++r) {
            int idx = tid + r * 256;
            int row = idx >> 4;
            int kp  = idx & 15;
            int gn = node0 + row;
            float2 xv = make_float2(0.f, 0.f);
            if (gn < n) xv = *(const float2*)&x[(size_t)gn * DIN + kt + kp * 2];
            half2v p; p[0] = (_Float16)xv.x; p[1] = (_Float16)xv.y;
            *(half2v*)&xs[row * 40 + kp * 2] = p;
        }
#pragma unroll
        for (int r = 0; r < 2; ++r) {
            int id = tid + r * 256;
            int c = id >> 2;
            int q = id & 3;
            half8 wv = *(const half8*)&Wt[(size_t)c * 256 + kt + q * 8];
            *(half8*)&Wl[c * 40 + q * 8] = wv;
        }
        __syncthreads();
        half8 af = *(const half8*)&xs[(wave * 16 + l15) * 40 + quad * 8];
#pragma unroll
        for (int ct = 0; ct < 8; ++ct) {
            half8 bf = *(const half8*)&Wl[(ct * 16 + l15) * 40 + quad * 8];
            acc[ct] = __builtin_amdgcn_mfma_f32_16x16x32_f16(af, bf, acc[ct], 0, 0, 0);
        }
    }
    __syncthreads();
#pragma unroll
    for (int ct = 0; ct < 8; ++ct)
#pragma unroll
        for (int r = 0; r < 4; ++r) {
            int row = wave * 16 + quad * 4 + r;
            ep[row * 136 + ct * 16 + l15] = (_Float16)acc[ct][r];
        }
    __syncthreads();
    {
        int row = tid >> 2, ch = tid & 3;
        int node = node0 + row;
        if (node < n) {
            const uint4* s = (const uint4*)&ep[row * 136 + ch * 32];
            uint4* d = (uint4*)&xph[(size_t)node * HC + ch * 32];
            d[0] = s[0]; d[1] = s[1]; d[2] = s[2]; d[3] = s[3];
        }
    }
    {
        int nl = tid >> 2, h = tid & 3;
        int node = node0 + nl;
        if (node < n) {
            float ps = 0.f, pd = 0.f;
            const _Float16* er = &ep[nl * 136 + h * 32];
#pragma unroll
            for (int c = 0; c < 32; ++c) {
                float v = (float)er[c];
                ps += v * attSL[h * 32 + c];
                pd += v * attDL[h * 32 + c];
            }
            a_src[node * NH + h] = ps;
            a_dst[node * NH + h] = pd;
        }
    }
}

// ---------------- CSR build: two-level counting sort ----------------
__global__ __launch_bounds__(256) void hist_kernel(const int* __restrict__ ei,
                                                   int* __restrict__ ghist, int e, int n) {
    __shared__ int h[256];
    const int tid = threadIdx.x;
    h[tid] = 0;
    __syncthreads();
    const int base = blockIdx.x * 4096;
#pragma unroll
    for (int j = 0; j < 16; ++j) {
        int i = base + j * 256 + tid;
        if (i < e) {
            int dst = ei[e + i];
            if ((unsigned)dst < (unsigned)n) atomicAdd(&h[dst >> BSH], 1);
        }
    }
    __syncthreads();
    if (h[tid]) atomicAdd(&ghist[tid], h[tid]);
}

__global__ __launch_bounds__(256) void bscan_kernel(const int* __restrict__ ghist,
                                                    int* __restrict__ gbase,
                                                    int* __restrict__ gcur, int nbuck) {
    __shared__ int buf[256];
    const int tid = threadIdx.x;
    int v = (tid < nbuck) ? ghist[tid] : 0;
    buf[tid] = v;
    __syncthreads();
    for (int s = 1; s < 256; s <<= 1) {
        int t = (tid >= s) ? buf[tid - s] : 0;
        __syncthreads();
        buf[tid] += t;
        __syncthreads();
    }
    int excl = buf[tid] - v;
    if (tid < nbuck) { gbase[tid] = excl; gcur[tid] = excl; }
    if (tid == nbuck - 1) gbase[nbuck] = buf[tid];
}

__global__ __launch_bounds__(256) void bin_kernel(const int* __restrict__ ei,
                                                  int* __restrict__ gcur,
                                                  unsigned* __restrict__ binned,
                                                  int e, int n) {
    __shared__ int h[256];
    __shared__ int rbase[256];
    const int tid = threadIdx.x;
    h[tid] = 0;
    __syncthreads();
    const int base = blockIdx.x * 4096;
    unsigned pk[16];
    int bk[16];
#pragma unroll
    for (int j = 0; j < 16; ++j) {
        int i = base + j * 256 + tid;
        bk[j] = -1;
        if (i < e) {
            int src = ei[i];
            int dst = ei[e + i];
            if ((unsigned)dst < (unsigned)n && (unsigned)src < (unsigned)n) {
                bk[j] = dst >> BSH;
                pk[j] = ((unsigned)(dst & (BSZ - 1)) << 24) | (unsigned)src;
                atomicAdd(&h[bk[j]], 1);
            }
        }
    }
    __syncthreads();
    if (h[tid]) rbase[tid] = atomicAdd(&gcur[tid], h[tid]);
    h[tid] = 0;
    __syncthreads();
#pragma unroll
    for (int j = 0; j < 16; ++j) {
        if (bk[j] >= 0) {
            int p = atomicAdd(&h[bk[j]], 1);
            binned[rbase[bk[j]] + p] = pk[j];
        }
    }
}

// per-bucket LDS counting sort; srt packed (dst<<16)|src (requires N<=65536)
// R11: widened to 1024 threads/block for 4x loop parallelism.
__global__ __launch_bounds__(1024) void csr_kernel(const unsigned* __restrict__ binned,
                                                   const int* __restrict__ gbase,
                                                   int* __restrict__ off,
                                                   unsigned* __restrict__ srt,
                                                   int n, int nbuck) {
    __shared__ int cnt[256], buf[256], cur[256];
    const int tid = threadIdx.x;
    const int b = blockIdx.x;
    const int kb = gbase[b];
    const int ke = gbase[b + 1];
    if (tid < 256) cnt[tid] = 0;
    __syncthreads();
    for (int i = kb + tid; i < ke; i += 1024)
        atomicAdd(&cnt[binned[i] >> 24], 1);
    __syncthreads();
    int v = 0;
    if (tid < 256) { v = cnt[tid]; buf[tid] = v; }
    __syncthreads();
    for (int s = 1; s < 256; s <<= 1) {
        int t = (tid < 256 && tid >= s) ? buf[tid - s] : 0;
        __syncthreads();
        if (tid < 256) buf[tid] += t;
        __syncthreads();
    }
    if (tid < 256) {
        const int excl = kb + buf[tid] - v;
        const int node = b * BSZ + tid;
        if (node < n) off[node] = excl;
        if (tid == 0 && b == nbuck - 1) off[n] = ke;
        cur[tid] = excl;
    }
    __syncthreads();
    const unsigned dbase = (unsigned)(b * BSZ) << 16;
    for (int i = kb + tid; i < ke; i += 1024) {
        unsigned pv = binned[i];
        int nl = pv >> 24;
        int pos = atomicAdd(&cur[nl], 1);
        srt[pos] = (dbase + ((unsigned)nl << 16)) | (pv & 0xFFFFu);
    }
}

// edge-parallel score computation: escore[i*4+h] = exp(leaky(a_src[src][h]+a_dst[dst][h]))
__global__ __launch_bounds__(256) void escore_kernel(const unsigned* __restrict__ srt,
                                                     const float* __restrict__ a_src,
                                                     const float* __restrict__ a_dst,
                                                     __half* __restrict__ escore,
                                                     int e, int n) {
    int i = blockIdx.x * 256 + threadIdx.x;
    if (i >= e) return;
    unsigned v = srt[i];
    int src = (int)(v & 0xFFFFu);
    int dst = (int)(v >> 16);
    if (src >= n || dst >= n) return;
    const float4 as = *(const float4*)&a_src[(size_t)src * 4];
    const float4 ad = *(const float4*)&a_dst[(size_t)dst * 4];
    float t0 = as.x + ad.x; t0 = (t0 > 0.f) ? t0 : NEG * t0;
    float t1 = as.y + ad.y; t1 = (t1 > 0.f) ? t1 : NEG * t1;
    float t2 = as.z + ad.z; t2 = (t2 > 0.f) ? t2 : NEG * t2;
    float t3 = as.w + ad.w; t3 = (t3 > 0.f) ? t3 : NEG * t3;
    __half2* ep = (__half2*)&escore[(size_t)i * 4];
    ep[0] = __floats2half2_rn(__expf(t0), __expf(t1));
    ep[1] = __floats2half2_rn(__expf(t2), __expf(t3));
}

// ---------------- aggregate: one wave per dst node ----------------
// R11: 4 edge-groups x 16 lanes. Lane = g*16 + l; lane covers channels [l*8, l*8+8)
// via one 16B gather; group g processes edges kb+g*4+j interleaved. Cross-group
// combine via 2-round shfl_xor(16,32). ~2.5-3x fewer wave-instructions per edge.
__global__ __launch_bounds__(256) void agg_kernel(const __half* __restrict__ xph,
                                                  const float* __restrict__ a_src,
                                                  const float* __restrict__ a_dst,
                                                  const int* __restrict__ off,
                                                  const unsigned* __restrict__ srt,
                                                  const __half* __restrict__ escore,
                                                  const float* __restrict__ bias,
                                                  float* __restrict__ out, int n) {
    const int gwave = (blockIdx.x * blockDim.x + threadIdx.x) >> 6;
    if (gwave >= n) return;
    const int node = gwave;
    const int lane = threadIdx.x & 63;
    const int g = lane >> 4;        // edge group 0..3
    const int l = lane & 15;        // channel-slice: channels [l*8, l*8+8)
    const int h = l >> 2;           // head owning those channels

    float acc[8];
#pragma unroll
    for (int c = 0; c < 8; ++c) acc[c] = 0.f;
    float den = 0.f;

    // self-loop contribution (group 0 only; merged in the reduction)
    if (g == 0) {
        float e0 = a_src[node * NH + h] + a_dst[node * NH + h];
        e0 = (e0 > 0.f) ? e0 : NEG * e0;
        float sl = __expf(e0);
        half8 xv = *(const half8*)&xph[(size_t)node * HC + l * 8];
#pragma unroll
        for (int c = 0; c < 8; ++c) acc[c] = sl * (float)xv[c];
        den = sl;
    }

    const int kb = off[node];
    const int ke = off[node + 1];
    int k0 = kb;
    for (; k0 + 16 <= ke; k0 += 16) {
        const int kg = k0 + g * 4;
        unsigned sv[4];
        float sc[4];
        half8 hv[4];
#pragma unroll
        for (int j = 0; j < 4; ++j) sv[j] = srt[kg + j];
#pragma unroll
        for (int j = 0; j < 4; ++j)
            hv[j] = *(const half8*)&xph[(size_t)(sv[j] & 0xFFFFu) * HC + l * 8];
#pragma unroll
        for (int j = 0; j < 4; ++j)
            sc[j] = __half2float(escore[(size_t)(kg + j) * 4 + h]);
#pragma unroll
        for (int j = 0; j < 4; ++j) {
            const float s = sc[j];
#pragma unroll
            for (int c = 0; c < 8; ++c) acc[c] += s * (float)hv[j][c];
            den += s;
        }
    }
    // tail: per-group single edges, stride 4
    for (int k = k0 + g; k < ke; k += 4) {
        const unsigned v = srt[k];
        const float s = __half2float(escore[(size_t)k * 4 + h]);
        const half8 hv = *(const half8*)&xph[(size_t)(v & 0xFFFFu) * HC + l * 8];
#pragma unroll
        for (int c = 0; c < 8; ++c) acc[c] += s * (float)hv[c];
        den += s;
    }

    // cross-group reduction: lanes with equal l sum over the 4 groups
#pragma unroll
    for (int c = 0; c < 8; ++c) acc[c] += __shfl_xor(acc[c], 16, 64);
    den += __shfl_xor(den, 16, 64);
#pragma unroll
    for (int c = 0; c < 8; ++c) acc[c] += __shfl_xor(acc[c], 32, 64);
    den += __shfl_xor(den, 32, 64);

    if (lane < 16) {
        const float inv = 1.0f / den;
        const float4* b4 = (const float4*)&bias[l * 8];
        float4 o0, o1;
        o0.x = acc[0] * inv + b4[0].x;
        o0.y = acc[1] * inv + b4[0].y;
        o0.z = acc[2] * inv + b4[0].z;
        o0.w = acc[3] * inv + b4[0].w;
        o1.x = acc[4] * inv + b4[1].x;
        o1.y = acc[5] * inv + b4[1].y;
        o1.z = acc[6] * inv + b4[1].z;
        o1.w = acc[7] * inv + b4[1].w;
        float4* d = (float4*)&out[(size_t)node * HC + l * 8];
        d[0] = o0;
        d[1] = o1;
    }
}

// ---------------- launch ----------------
extern "C" void kernel_launch(void* const* d_in, const int* in_sizes, int n_in,
                              void* d_out, int out_size, void* d_ws, size_t ws_size,
                              hipStream_t stream) {
    if (n_in < 6 || !d_out || !d_ws) return;
    const float* x    = (const float*)d_in[0];
    const int*   ei   = (const int*)d_in[1];
    const float* W    = (const float*)d_in[2];
    const float* attS = (const float*)d_in[3];
    const float* attD = (const float*)d_in[4];
    const float* bias = (const float*)d_in[5];
    float* out = (float*)d_out;

    const int N = in_sizes[0] / DIN;
    const int E = in_sizes[1] / 2;
    if (N <= 0 || E <= 0) return;
    const int NBUCK = (N + BSZ - 1) >> BSH;
    if (NBUCK > 256 || N > 65536) return;   // dst<<16 packing requires N<=65536

    char* ws = (char*)d_ws;
    size_t off_b = 0;
    auto carve = [&](size_t bytes) {
        size_t p = off_b;
        off_b = (off_b + bytes + 255) & ~(size_t)255;
        return (void*)(ws + p);
    };
    __half*    xph    = (__half*)carve((size_t)N * HC * 2);
    _Float16*  Wt     = (_Float16*)carve((size_t)HC * DIN * 2);
    float*     a_src  = (float*)carve((size_t)N * NH * 4);
    float*     a_dst  = (float*)carve((size_t)N * NH * 4);
    int*       ghist  = (int*)carve(257 * 4);
    int*       gbase  = (int*)carve(257 * 4);
    int*       gcur   = (int*)carve(257 * 4);
    unsigned*  binned = (unsigned*)carve((size_t)E * 4);
    int*       offp   = (int*)carve((size_t)(N + 1) * 4);
    unsigned*  srt    = (unsigned*)carve((size_t)E * 4);
    __half*    escore = (__half*)carve((size_t)E * NH * 2);
    (void)out_size;
    if (off_b > ws_size) return;

    const int ECH = (E + 4095) / 4096;

    wtrans_kernel<<<(DIN * HC) / 256, 256, 0, stream>>>(W, Wt, ghist);
    proj_kernel<<<(N + 63) / 64, 256, 0, stream>>>(x, Wt, attS, attD, (__half*)xph, a_src, a_dst, N);
    hist_kernel<<<ECH, 256, 0, stream>>>(ei, ghist, E, N);
    bscan_kernel<<<1, 256, 0, stream>>>(ghist, gbase, gcur, NBUCK);
    bin_kernel<<<ECH, 256, 0, stream>>>(ei, gcur, binned, E, N);
    csr_kernel<<<NBUCK, 1024, 0, stream>>>(binned, gbase, offp, srt, N, NBUCK);
    escore_kernel<<<(E + 255) / 256, 256, 0, stream>>>(srt, a_src, a_dst, escore, E, N);
    agg_kernel<<<(N * 64 + 255) / 256, 256, 0, stream>>>(xph, a_src, a_dst,
                                                         offp, srt, escore, bias, out, N);
}

// Round 2
// 233.431 us; speedup vs baseline: 1.0872x; 1.0309x over previous
//
#include <hip/hip_runtime.h>
#include <hip/hip_fp16.h>

// GATConv: N=50000, E=1600000, DIM_IN=256, HEADS=4, DIM_OUT=32 (HC=128)
// R12: pipeline restructure 8 -> 5 dispatches:
//   D0 zero(ghist,gcur0); D1 hist||wtrans; D2 bin||proj_p1; D3 csr||proj_p2; D4 agg.
//   bscan removed (bin/csr recompute 256-entry scan locally in LDS).
//   escore kernel removed (exp(leaky(.)) inlined into agg, f32 scores).
//   srt stored as uint16 (src only).

#define DIN 256
#define HC 128
#define NH 4
#define NEG 0.2f
#define BSH 8
#define BSZ 256

typedef _Float16 half8 __attribute__((ext_vector_type(8)));
typedef _Float16 half2v __attribute__((ext_vector_type(2)));
typedef float f32x4 __attribute__((ext_vector_type(4)));

// ---------------- zero small arrays ----------------
__global__ void zero_kernel(int* __restrict__ p, int n) {
    int i = blockIdx.x * blockDim.x + threadIdx.x;
    if (i < n) p[i] = 0;
}

// ---------------- projection body (MFMA) + fused attention logits ----------------
// sm layout: xs [64][40] halves @0 (5120B); Wl [128][40] halves @5120 (10240B);
//            ep [64][136] halves @0 (17408B, reused after MFMA);
//            attSL @17408 (512B), attDL @17920 (512B). Total 18432B.
__device__ __forceinline__ void proj_body(char* sm, const float* __restrict__ x,
                                          const _Float16* __restrict__ Wt,
                                          const float* __restrict__ attS,
                                          const float* __restrict__ attD,
                                          __half* __restrict__ xph,
                                          float* __restrict__ a_src,
                                          float* __restrict__ a_dst, int n, int node0) {
    _Float16* xs = (_Float16*)sm;
    _Float16* Wl = (_Float16*)(sm + 5120);
    _Float16* ep = (_Float16*)sm;
    float* attSL = (float*)(sm + 17408);
    float* attDL = (float*)(sm + 17920);

    const int tid  = threadIdx.x;
    const int wave = tid >> 6;
    const int lane = tid & 63;
    const int l15  = lane & 15;
    const int quad = lane >> 4;

    if (tid < 128) attSL[tid] = attS[tid];
    else           attDL[tid - 128] = attD[tid - 128];

    f32x4 acc[8];
#pragma unroll
    for (int ct = 0; ct < 8; ++ct) acc[ct] = (f32x4){0.f, 0.f, 0.f, 0.f};

    for (int kt = 0; kt < DIN; kt += 32) {
        __syncthreads();
#pragma unroll
        for (int r = 0; r < 4; ++r) {
            int idx = tid + r * 256;
            int row = idx >> 4;
            int kp  = idx & 15;
            int gn = node0 + row;
            float2 xv = make_float2(0.f, 0.f);
            if (gn < n) xv = *(const float2*)&x[(size_t)gn * DIN + kt + kp * 2];
            half2v p; p[0] = (_Float16)xv.x; p[1] = (_Float16)xv.y;
            *(half2v*)&xs[row * 40 + kp * 2] = p;
        }
#pragma unroll
        for (int r = 0; r < 2; ++r) {
            int id = tid + r * 256;
            int c = id >> 2;
            int q = id & 3;
            half8 wv = *(const half8*)&Wt[(size_t)c * 256 + kt + q * 8];
            *(half8*)&Wl[c * 40 + q * 8] = wv;
        }
        __syncthreads();
        half8 af = *(const half8*)&xs[(wave * 16 + l15) * 40 + quad * 8];
#pragma unroll
        for (int ct = 0; ct < 8; ++ct) {
            half8 bf = *(const half8*)&Wl[(ct * 16 + l15) * 40 + quad * 8];
            acc[ct] = __builtin_amdgcn_mfma_f32_16x16x32_f16(af, bf, acc[ct], 0, 0, 0);
        }
    }
    __syncthreads();
#pragma unroll
    for (int ct = 0; ct < 8; ++ct)
#pragma unroll
        for (int r = 0; r < 4; ++r) {
            int row = wave * 16 + quad * 4 + r;
            ep[row * 136 + ct * 16 + l15] = (_Float16)acc[ct][r];
        }
    __syncthreads();
    {
        int row = tid >> 2, ch = tid & 3;
        int node = node0 + row;
        if (node < n) {
            const uint4* s = (const uint4*)&ep[row * 136 + ch * 32];
            uint4* d = (uint4*)&xph[(size_t)node * HC + ch * 32];
            d[0] = s[0]; d[1] = s[1]; d[2] = s[2]; d[3] = s[3];
        }
    }
    {
        int nl = tid >> 2, h = tid & 3;
        int node = node0 + nl;
        if (node < n) {
            float ps = 0.f, pd = 0.f;
            const _Float16* er = &ep[nl * 136 + h * 32];
#pragma unroll
            for (int c = 0; c < 32; ++c) {
                float v = (float)er[c];
                ps += v * attSL[h * 32 + c];
                pd += v * attDL[h * 32 + c];
            }
            a_src[node * NH + h] = ps;
            a_dst[node * NH + h] = pd;
        }
    }
}

// ---------------- D1: hist || wtrans ----------------
__global__ __launch_bounds__(256) void k_hist_wtrans(const int* __restrict__ ei,
                                                     int* __restrict__ ghist,
                                                     const float* __restrict__ W,
                                                     _Float16* __restrict__ Wt,
                                                     int e, int n, int ech) {
    if ((int)blockIdx.x < ech) {
        __shared__ int h[256];
        const int tid = threadIdx.x;
        h[tid] = 0;
        __syncthreads();
        const int base = blockIdx.x * 4096;
#pragma unroll
        for (int j = 0; j < 16; ++j) {
            int i = base + j * 256 + tid;
            if (i < e) {
                int dst = ei[e + i];
                if ((unsigned)dst < (unsigned)n) atomicAdd(&h[dst >> BSH], 1);
            }
        }
        __syncthreads();
        if (h[tid]) atomicAdd(&ghist[tid], h[tid]);
    } else {
        int i = ((int)blockIdx.x - ech) * 256 + threadIdx.x;
        int k = i >> 7, c = i & 127;
        Wt[c * 256 + k] = (_Float16)W[i];
    }
}

// ---------------- D2: bin (with local scan) || proj part 1 ----------------
__global__ __launch_bounds__(256) void k_bin_proj(const int* __restrict__ ei,
                                                  const int* __restrict__ ghist,
                                                  int* __restrict__ gcur0,
                                                  unsigned* __restrict__ binned,
                                                  const float* __restrict__ x,
                                                  const _Float16* __restrict__ Wt,
                                                  const float* __restrict__ attS,
                                                  const float* __restrict__ attD,
                                                  __half* __restrict__ xph,
                                                  float* __restrict__ a_src,
                                                  float* __restrict__ a_dst,
                                                  int e, int n, int ech) {
    __shared__ __attribute__((aligned(16))) char sm[18432];
    if ((int)blockIdx.x < ech) {
        int* h     = (int*)sm;
        int* rbase = (int*)(sm + 1024);
        int* buf   = (int*)(sm + 2048);
        const int tid = threadIdx.x;
        const int gh = ghist[tid];
        buf[tid] = gh;
        h[tid] = 0;
        __syncthreads();
        for (int s = 1; s < 256; s <<= 1) {
            int t = (tid >= s) ? buf[tid - s] : 0;
            __syncthreads();
            buf[tid] += t;
            __syncthreads();
        }
        const int gbase_t = buf[tid] - gh;   // exclusive scan
        const int base = blockIdx.x * 4096;
        unsigned pk[16];
        int bk[16];
#pragma unroll
        for (int j = 0; j < 16; ++j) {
            int i = base + j * 256 + tid;
            bk[j] = -1;
            if (i < e) {
                int src = ei[i];
                int dst = ei[e + i];
                if ((unsigned)dst < (unsigned)n && (unsigned)src < (unsigned)n) {
                    bk[j] = dst >> BSH;
                    pk[j] = ((unsigned)(dst & (BSZ - 1)) << 24) | (unsigned)src;
                    atomicAdd(&h[bk[j]], 1);
                }
            }
        }
        __syncthreads();
        if (h[tid]) rbase[tid] = gbase_t + atomicAdd(&gcur0[tid], h[tid]);
        h[tid] = 0;
        __syncthreads();
#pragma unroll
        for (int j = 0; j < 16; ++j) {
            if (bk[j] >= 0) {
                int p = atomicAdd(&h[bk[j]], 1);
                binned[rbase[bk[j]] + p] = pk[j];
            }
        }
    } else {
        proj_body(sm, x, Wt, attS, attD, xph, a_src, a_dst, n, ((int)blockIdx.x - ech) * 64);
    }
}

// ---------------- D3: csr (with local scan) || proj part 2 ----------------
__global__ __launch_bounds__(256) void k_csr_proj(const unsigned* __restrict__ binned,
                                                  const int* __restrict__ ghist,
                                                  int* __restrict__ off,
                                                  unsigned short* __restrict__ srt,
                                                  const float* __restrict__ x,
                                                  const _Float16* __restrict__ Wt,
                                                  const float* __restrict__ attS,
                                                  const float* __restrict__ attD,
                                                  __half* __restrict__ xph,
                                                  float* __restrict__ a_src,
                                                  float* __restrict__ a_dst,
                                                  int n, int nbuck, int pb1) {
    __shared__ __attribute__((aligned(16))) char sm[18432];
    if ((int)blockIdx.x < nbuck) {
        int* cnt = (int*)sm;
        int* buf = (int*)(sm + 1024);
        int* cur = (int*)(sm + 2048);
        const int tid = threadIdx.x;
        const int b = blockIdx.x;
        buf[tid] = ghist[tid];
        __syncthreads();
        for (int s = 1; s < 256; s <<= 1) {
            int t = (tid >= s) ? buf[tid - s] : 0;
            __syncthreads();
            buf[tid] += t;
            __syncthreads();
        }
        const int ke = buf[b];              // inclusive scan at b
        const int kb = ke - ghist[b];
        __syncthreads();                    // protect buf before reuse
        cnt[tid] = 0;
        __syncthreads();
        for (int i = kb + tid; i < ke; i += 256)
            atomicAdd(&cnt[binned[i] >> 24], 1);
        __syncthreads();
        int v = cnt[tid];
        buf[tid] = v;
        __syncthreads();
        for (int s = 1; s < 256; s <<= 1) {
            int t = (tid >= s) ? buf[tid - s] : 0;
            __syncthreads();
            buf[tid] += t;
            __syncthreads();
        }
        const int excl = kb + buf[tid] - v;
        const int node = b * BSZ + tid;
        if (node < n) off[node] = excl;
        if (tid == 0 && b == nbuck - 1) off[n] = ke;
        cur[tid] = excl;
        __syncthreads();
        for (int i = kb + tid; i < ke; i += 256) {
            unsigned pv = binned[i];
            int nl = pv >> 24;
            int pos = atomicAdd(&cur[nl], 1);
            srt[pos] = (unsigned short)(pv & 0xFFFFu);
        }
    } else {
        proj_body(sm, x, Wt, attS, attD, xph, a_src, a_dst, n,
                  (pb1 + (int)blockIdx.x - nbuck) * 64);
    }
}

// ---------------- D4: aggregate, scores inlined (f32) ----------------
// 4 edge-groups x 16 lanes; lane covers channels [l*8, l*8+8) via 16B gather.
__global__ __launch_bounds__(256) void agg_kernel(const __half* __restrict__ xph,
                                                  const float* __restrict__ a_src,
                                                  const float* __restrict__ a_dst,
                                                  const int* __restrict__ off,
                                                  const unsigned short* __restrict__ srt,
                                                  const float* __restrict__ bias,
                                                  float* __restrict__ out, int n) {
    const int gwave = (blockIdx.x * blockDim.x + threadIdx.x) >> 6;
    if (gwave >= n) return;
    const int node = gwave;
    const int lane = threadIdx.x & 63;
    const int g = lane >> 4;
    const int l = lane & 15;
    const int h = l >> 2;

    const float ad = a_dst[node * NH + h];

    float acc[8];
#pragma unroll
    for (int c = 0; c < 8; ++c) acc[c] = 0.f;
    float den = 0.f;

    if (g == 0) {   // self loop
        float t = a_src[node * NH + h] + ad;
        t = fmaxf(t, 0.f) + NEG * fminf(t, 0.f);
        float s = __expf(t);
        half8 xv = *(const half8*)&xph[(size_t)node * HC + l * 8];
#pragma unroll
        for (int c = 0; c < 8; ++c) acc[c] = s * (float)xv[c];
        den = s;
    }

    const int kb = off[node];
    const int ke = off[node + 1];
    int k0 = kb;
    for (; k0 + 16 <= ke; k0 += 16) {
        const int kg = k0 + g * 4;
        int sv[4];
        float asv[4];
        half8 hv[4];
#pragma unroll
        for (int j = 0; j < 4; ++j) sv[j] = srt[kg + j];
#pragma unroll
        for (int j = 0; j < 4; ++j) asv[j] = a_src[sv[j] * NH + h];
#pragma unroll
        for (int j = 0; j < 4; ++j)
            hv[j] = *(const half8*)&xph[(size_t)sv[j] * HC + l * 8];
#pragma unroll
        for (int j = 0; j < 4; ++j) {
            float t = asv[j] + ad;
            t = fmaxf(t, 0.f) + NEG * fminf(t, 0.f);
            const float s = __expf(t);
#pragma unroll
            for (int c = 0; c < 8; ++c) acc[c] += s * (float)hv[j][c];
            den += s;
        }
    }
    for (int k = k0 + g; k < ke; k += 4) {
        const int sv = srt[k];
        float t = a_src[sv * NH + h] + ad;
        t = fmaxf(t, 0.f) + NEG * fminf(t, 0.f);
        const float s = __expf(t);
        const half8 hv = *(const half8*)&xph[(size_t)sv * HC + l * 8];
#pragma unroll
        for (int c = 0; c < 8; ++c) acc[c] += s * (float)hv[c];
        den += s;
    }

#pragma unroll
    for (int c = 0; c < 8; ++c) acc[c] += __shfl_xor(acc[c], 16, 64);
    den += __shfl_xor(den, 16, 64);
#pragma unroll
    for (int c = 0; c < 8; ++c) acc[c] += __shfl_xor(acc[c], 32, 64);
    den += __shfl_xor(den, 32, 64);

    if (lane < 16) {
        const float inv = 1.0f / den;
        const float4* b4 = (const float4*)&bias[l * 8];
        float4 o0, o1;
        o0.x = acc[0] * inv + b4[0].x;
        o0.y = acc[1] * inv + b4[0].y;
        o0.z = acc[2] * inv + b4[0].z;
        o0.w = acc[3] * inv + b4[0].w;
        o1.x = acc[4] * inv + b4[1].x;
        o1.y = acc[5] * inv + b4[1].y;
        o1.z = acc[6] * inv + b4[1].z;
        o1.w = acc[7] * inv + b4[1].w;
        float4* d = (float4*)&out[(size_t)node * HC + l * 8];
        d[0] = o0;
        d[1] = o1;
    }
}

// ---------------- launch ----------------
extern "C" void kernel_launch(void* const* d_in, const int* in_sizes, int n_in,
                              void* d_out, int out_size, void* d_ws, size_t ws_size,
                              hipStream_t stream) {
    if (n_in < 6 || !d_out || !d_ws) return;
    const float* x    = (const float*)d_in[0];
    const int*   ei   = (const int*)d_in[1];
    const float* W    = (const float*)d_in[2];
    const float* attS = (const float*)d_in[3];
    const float* attD = (const float*)d_in[4];
    const float* bias = (const float*)d_in[5];
    float* out = (float*)d_out;

    const int N = in_sizes[0] / DIN;
    const int E = in_sizes[1] / 2;
    if (N <= 0 || E <= 0) return;
    const int NBUCK = (N + BSZ - 1) >> BSH;
    if (NBUCK > 256 || N > 65536) return;   // src fits 16 bits

    char* ws = (char*)d_ws;
    size_t off_b = 0;
    auto carve = [&](size_t bytes) {
        size_t p = off_b;
        off_b = (off_b + bytes + 255) & ~(size_t)255;
        return (void*)(ws + p);
    };
    __half*         xph    = (__half*)carve((size_t)N * HC * 2);
    _Float16*       Wt     = (_Float16*)carve((size_t)HC * DIN * 2);
    float*          a_src  = (float*)carve((size_t)N * NH * 4);
    float*          a_dst  = (float*)carve((size_t)N * NH * 4);
    int*            gz     = (int*)carve(512 * 4);        // ghist[256] + gcur0[256]
    unsigned*       binned = (unsigned*)carve((size_t)E * 4);
    int*            offp   = (int*)carve((size_t)(N + 1) * 4);
    unsigned short* srt    = (unsigned short*)carve((size_t)E * 2);
    (void)out_size;
    if (off_b > ws_size) return;

    int* ghist = gz;
    int* gcur0 = gz + 256;

    const int ECH = (E + 4095) / 4096;
    const int PB  = (N + 63) / 64;
    const int PB1 = PB / 2;

    zero_kernel<<<2, 256, 0, stream>>>(gz, 512);
    k_hist_wtrans<<<ECH + 128, 256, 0, stream>>>(ei, ghist, W, Wt, E, N, ECH);
    k_bin_proj<<<ECH + PB1, 256, 0, stream>>>(ei, ghist, gcur0, binned,
                                              x, Wt, attS, attD, xph, a_src, a_dst,
                                              E, N, ECH);
    k_csr_proj<<<NBUCK + (PB - PB1), 256, 0, stream>>>(binned, ghist, offp, srt,
                                                       x, Wt, attS, attD, xph, a_src, a_dst,
                                                       N, NBUCK, PB1);
    agg_kernel<<<(N * 64 + 255) / 256, 256, 0, stream>>>(xph, a_src, a_dst,
                                                         offp, srt, bias, out, N);
}